// Round 9
// baseline (63.110 us; speedup 1.0000x reference)
//
#include <hip/hip_runtime.h>
#include <math.h>

#define Bn 32
#define Ln 524288
#define NF 4

#define TPB   256               // 4 waves
#define NW    (TPB / 64)        // 4
#define CPT   34                // samples per thread
#define OUT   8192              // output samples per WG
#define WU    512               // warm-up samples (truncated prefix)
#define S_WG  (OUT + WU)        // 8704 staged samples
#define TPR   (Ln / OUT)        // 64 tiles per row
#define NT    (Bn * TPR)        // 2048 WGs

#define SLOT2  (S_WG / 2)       // 4352 float2 slots
#define OSLOT4 (OUT / 4)        // 2048
#define WSLOT4 (WU / 4)         // 128

// ws layout (float indices) — nothing inter-WG.
#define COEF_OFF 0               // 20
#define POWJ_OFF 64              // j=0..5: A^(34*2^j), full 8x8  (384)
#define XW1_OFF  448             // A^2176 (wave span), full 8x8  (64)
#define PLM4_OFF 512             // packed PLM: 10 groups x 64 lanes x float4 (2560)

// LDS: float2 slots with pad every 16 (phys = s + s/16), + scan scratch
#define PHYS_MAX 4624            // float2 capacity (4352 + 272)
#define WAGG_L   (PHYS_MAX * 2)  // float idx: 4 waves * 8
#define PA_L     (WAGG_L + 32)   // 4 waves * 8
#define LDS_F    (PA_L + 32)     // 9312 floats = 37.2 KB -> 4 WG/CU

__device__ __forceinline__ int phys(int s2) { return s2 + (s2 >> 4); }

// packed block-lower-triangular layout: row starts / col counts
// rows use cols 0..(r|1) -> 2,2,4,4,6,6,8,8 = 40 elements
__device__ __constant__ const int PRB[8] = {0, 2, 4, 8, 12, 18, 24, 32};
__device__ __constant__ const int PNC[8] = {2, 2, 4, 4, 6, 6, 8, 8};

// ---------------------------------------------------------------------------
// Precompute (1 block, 64 thr): f32-rounded coefs; A^34 via unit-state sim
// (double); squaring chain A^(34*2^j) j=0..5, XW1=A^2176; per-lane matrices
// PLM[l]=A^(34l) packed (40 nonzeros) transposed [group4][lane][4].
// ---------------------------------------------------------------------------
__global__ void precompute_k(const float* __restrict__ lr,
                             const float* __restrict__ ra,
                             const float* __restrict__ b0,
                             const float* __restrict__ b1,
                             const float* __restrict__ b2,
                             float* __restrict__ ws) {
    __shared__ double A34d[64], Md[64], Td[64], Pd[64];
    const int t = threadIdx.x;

    if (t < NF) {
        double r   = 0.999 / (1.0 + exp(-(double)lr[t]));
        double ang = 3.14159265358979323846 / (1.0 + exp(-(double)ra[t]));
        ws[COEF_OFF + t * 5 + 0] = b0[t];
        ws[COEF_OFF + t * 5 + 1] = b1[t];
        ws[COEF_OFF + t * 5 + 2] = b2[t];
        ws[COEF_OFF + t * 5 + 3] = (float)(-2.0 * r * cos(ang));
        ws[COEF_OFF + t * 5 + 4] = (float)(r * r);
    }
    __syncthreads();

    if (t < 8) {
        double cb0[NF], cb1[NF], cb2[NF], ca1[NF], ca2[NF];
        for (int f = 0; f < NF; ++f) {
            cb0[f] = (double)ws[COEF_OFF + f * 5 + 0];
            cb1[f] = (double)ws[COEF_OFF + f * 5 + 1];
            cb2[f] = (double)ws[COEF_OFF + f * 5 + 2];
            ca1[f] = (double)ws[COEF_OFF + f * 5 + 3];
            ca2[f] = (double)ws[COEF_OFF + f * 5 + 4];
        }
        double s[8];
        for (int r = 0; r < 8; ++r) s[r] = 0.0;
        s[t] = 1.0;
        for (int n = 0; n < CPT; ++n) {
            double v = 0.0;
            for (int f = 0; f < NF; ++f) {
                double y     = cb0[f] * v + s[2 * f];
                s[2 * f]     = cb1[f] * v - ca1[f] * y + s[2 * f + 1];
                s[2 * f + 1] = cb2[f] * v - ca2[f] * y;
                v = y;
            }
        }
        for (int r = 0; r < 8; ++r) A34d[r * 8 + t] = s[r];  // column t of A^34
    }
    __syncthreads();

    Md[t] = A34d[t];
    __syncthreads();
    ws[POWJ_OFF + t] = (float)Md[t];  // j=0: A^34

    const int r8 = t >> 3, c8 = t & 7;
    for (int sq = 1; sq <= 6; ++sq) {
        double acc = 0.0;
        for (int m = 0; m < 8; ++m) acc += Md[r8 * 8 + m] * Md[m * 8 + c8];
        Td[t] = acc;
        __syncthreads();
        Md[t] = Td[t];
        __syncthreads();
        if (sq <= 5) ws[POWJ_OFF + sq * 64 + t] = (float)Md[t];  // A^(34*2^sq)
        else         ws[XW1_OFF + t]            = (float)Md[t];  // A^2176
    }

    // PLM[l] = A^(34l), packed-transposed. PLM[0] = I.
    Pd[t] = (r8 == c8) ? 1.0 : 0.0;
    __syncthreads();
    for (int l = 0; l < 64; ++l) {
        if (t < 40) {
            // map packed idx t -> (r,c)
            int rr = 0;
#pragma unroll
            for (int r = 1; r < 8; ++r) if (t >= PRB[r]) rr = r;
            const int cc = t - PRB[rr];
            ws[PLM4_OFF + (t >> 2) * 256 + l * 4 + (t & 3)] = (float)Pd[rr * 8 + cc];
        }
        // Pd = Pd * A34
        double acc = 0.0;
        for (int m = 0; m < 8; ++m) acc += Pd[r8 * 8 + m] * A34d[m * 8 + c8];
        Td[t] = acc;
        __syncthreads();
        Pd[t] = Td[t];
        __syncthreads();
    }
}

// ---------------------------------------------------------------------------
__device__ __forceinline__ void step1(float& u, float* s,
                                      const float* c0, const float* c1,
                                      const float* c2, const float* A1,
                                      const float* A2) {
#pragma unroll
    for (int f = 0; f < NF; ++f) {
        float yv     = fmaf(c0[f], u, s[2 * f]);
        s[2 * f]     = fmaf(-A1[f], yv, fmaf(c1[f], u, s[2 * f + 1]));
        s[2 * f + 1] = fmaf(-A2[f], yv, c2[f] * u);
        u = yv;
    }
}

// Sparse (block-lower-triangular) matvecs; T wave-uniform (global) -> scalar.
__device__ __forceinline__ void matvec_acc_sp(float* o, const float* __restrict__ T,
                                              const float* p) {
#pragma unroll
    for (int r = 0; r < 8; ++r) {
        const int ncol = (r | 1) + 1;
#pragma unroll
        for (int c = 0; c < 8; ++c)
            if (c < ncol) o[r] = fmaf(T[r * 8 + c], p[c], o[r]);
    }
}
__device__ __forceinline__ void matvec_rep_sp(float* h, const float* __restrict__ T) {
    float tmp[8];
#pragma unroll
    for (int r = 0; r < 8; ++r) {
        const int ncol = (r | 1) + 1;
        float acc = 0.f;
#pragma unroll
        for (int c = 0; c < 8; ++c)
            if (c < ncol) acc = fmaf(T[r * 8 + c], h[c], acc);
        tmp[r] = acc;
    }
#pragma unroll
    for (int r = 0; r < 8; ++r) h[r] = tmp[r];
}

// ---------------------------------------------------------------------------
// One WG = 8192-sample output tile + 512-sample warm-up. No inter-WG comm.
// x staged in LDS (float2 slots, pad/16); both passes read LDS.
// ---------------------------------------------------------------------------
__global__ __launch_bounds__(TPB, 4) void biquad_k(const float* __restrict__ x,
                                                   const float* __restrict__ ws,
                                                   float* __restrict__ y) {
    __shared__ __align__(16) float ldsf[LDS_F];
    float2* lds2 = (float2*)ldsf;
    const int t    = threadIdx.x;
    const int lane = t & 63;
    const int w    = t >> 6;

    const int tile = blockIdx.x;
    const int row  = tile / TPR;
    const int tpos = tile % TPR;

    const float* __restrict__ mats = ws + POWJ_OFF;
    const float* __restrict__ xw1  = ws + XW1_OFF;

    // ---- stage x -> LDS (coalesced float4 reads + one float2 tail) ----
    const long base4 = (long)row * (Ln / 4) + (long)tpos * OSLOT4 - WSLOT4;
    const float4* xg4 = (const float4*)x;
#pragma unroll
    for (int j = 0; j < 8; ++j) {
        const int n4 = j * TPB + t;  // [0, 2048)
        float4 v = make_float4(0.f, 0.f, 0.f, 0.f);
        if (tpos > 0 || n4 >= WSLOT4) v = xg4[base4 + n4];
        const int s2 = 2 * n4;
        const int ph = phys(s2);          // pair (s2, s2+1) is phys-contiguous
        lds2[ph]     = make_float2(v.x, v.y);
        lds2[ph + 1] = make_float2(v.z, v.w);
    }
    {   // tail: float2 slots [4096, 4352)
        const long base2 = 2 * base4;
        const float2* xg2 = (const float2*)x;
        const int s2 = 4096 + t;
        lds2[phys(s2)] = xg2[base2 + s2];
    }

    float c0[NF], c1[NF], c2[NF], A1[NF], A2[NF];
#pragma unroll
    for (int f = 0; f < NF; ++f) {
        c0[f] = ws[COEF_OFF + f * 5 + 0];
        c1[f] = ws[COEF_OFF + f * 5 + 1];
        c2[f] = ws[COEF_OFF + f * 5 + 2];
        A1[f] = ws[COEF_OFF + f * 5 + 3];
        A2[f] = ws[COEF_OFF + f * 5 + 4];
    }
    __syncthreads();

    // ---- pass 1: zero-state chunk-final state ----
    float s[8];
#pragma unroll
    for (int r = 0; r < 8; ++r) s[r] = 0.f;
#pragma unroll
    for (int i = 0; i < CPT / 2; ++i) {
        const float2 v = lds2[phys(17 * t + i)];
        float u;
        u = v.x; step1(u, s, c0, c1, c2, A1, A2);
        u = v.y; step1(u, s, c0, c1, c2, A1, A2);
    }

    // ---- intra-wave affine Kogge-Stone over 64 chunks ----
    float v8[8];
#pragma unroll
    for (int r = 0; r < 8; ++r) v8[r] = s[r];
#pragma unroll
    for (int j = 0; j < 6; ++j) {
        const int st = 1 << j;
        float p[8];
#pragma unroll
        for (int r = 0; r < 8; ++r) p[r] = __shfl_up(v8[r], st, 64);
        if (lane >= st) matvec_acc_sp(v8, mats + j * 64, p);
    }

    if (lane == 63) {
#pragma unroll
        for (int r = 0; r < 8; ++r) ldsf[WAGG_L + w * 8 + r] = v8[r];
    }
    __syncthreads();

    // ---- cross-wave prefix (4 waves), oldest-first Horner with XW1 ----
    if (t < NW) {
        float acc[8];
#pragma unroll
        for (int r = 0; r < 8; ++r) acc[r] = 0.f;
        for (int m = 0; m < t; ++m) {
            matvec_rep_sp(acc, xw1);
#pragma unroll
            for (int r = 0; r < 8; ++r) acc[r] += ldsf[WAGG_L + m * 8 + r];
        }
#pragma unroll
        for (int r = 0; r < 8; ++r) ldsf[PA_L + t * 8 + r] = acc[r];
    }
    __syncthreads();

    // ---- per-thread entry: s = PLM[lane] * H_w + v8[lane-1] ----
    float m40[40];
    {
        const float4* plm4 = (const float4*)(ws + PLM4_OFF);
#pragma unroll
        for (int g = 0; g < 10; ++g) {
            const float4 mv = plm4[g * 64 + lane];
            m40[4 * g + 0] = mv.x; m40[4 * g + 1] = mv.y;
            m40[4 * g + 2] = mv.z; m40[4 * g + 3] = mv.w;
        }
    }
    float H[8];
#pragma unroll
    for (int r = 0; r < 8; ++r) H[r] = ldsf[PA_L + w * 8 + r];
    float se[8];
#pragma unroll
    for (int r = 0; r < 8; ++r) {
        float acc = 0.f;
        const int nc = (r | 1) + 1;
#pragma unroll
        for (int c = 0; c < 8; ++c)
            if (c < nc) acc = fmaf(m40[PRB[r] + c], H[c], acc);
        se[r] = acc;
    }
    float pv[8];
#pragma unroll
    for (int r = 0; r < 8; ++r) pv[r] = __shfl_up(v8[r], 1, 64);
#pragma unroll
    for (int r = 0; r < 8; ++r) s[r] = se[r] + ((lane > 0) ? pv[r] : 0.f);

    // ---- pass 2 from exact entry state; write y back into LDS slots ----
#pragma unroll
    for (int i = 0; i < CPT / 2; ++i) {
        const int ph = phys(17 * t + i);
        float2 v = lds2[ph];
        float u;
        u = v.x; step1(u, s, c0, c1, c2, A1, A2); v.x = u;
        u = v.y; step1(u, s, c0, c1, c2, A1, A2); v.y = u;
        lds2[ph] = v;
    }
    __syncthreads();

    // ---- coalesced write of output region (skip warm-up prefix) ----
    float4* yg4 = (float4*)y;
    const long obase4 = (long)row * (Ln / 4) + (long)tpos * OSLOT4;
#pragma unroll
    for (int j = 0; j < 8; ++j) {
        const int n4 = WSLOT4 + j * TPB + t;  // [128, 2176)
        const int ph = phys(2 * n4);
        const float2 a = lds2[ph];
        const float2 b = lds2[ph + 1];
        yg4[obase4 + (n4 - WSLOT4)] = make_float4(a.x, a.y, b.x, b.y);
    }
}

// ---------------------------------------------------------------------------
extern "C" void kernel_launch(void* const* d_in, const int* in_sizes, int n_in,
                              void* d_out, int out_size, void* d_ws, size_t ws_size,
                              hipStream_t stream) {
    const float* x  = (const float*)d_in[0];
    const float* lr = (const float*)d_in[1];
    const float* ra = (const float*)d_in[2];
    const float* b0 = (const float*)d_in[3];
    const float* b1 = (const float*)d_in[4];
    const float* b2 = (const float*)d_in[5];
    float* y  = (float*)d_out;
    float* ws = (float*)d_ws;

    precompute_k<<<dim3(1), dim3(64), 0, stream>>>(lr, ra, b0, b1, b2, ws);
    biquad_k<<<dim3(NT), dim3(TPB), 0, stream>>>(x, ws, y);
}

// Round 10
// 54.437 us; speedup vs baseline: 1.1593x; 1.1593x over previous
//
#include <hip/hip_runtime.h>
#include <math.h>

#define Bn 32
#define Ln 524288
#define NF 4

#define TPB   256               // 4 waves
#define NW    (TPB / 64)        // 4
#define CPT   18                // samples per thread (9 float2)
#define OUT   4096              // output samples per WG
#define WU    512               // warm-up samples
#define S_WG  (OUT + WU)        // 4608
#define TPR   (Ln / OUT)        // 128 tiles per row
#define NT    (Bn * TPR)        // 4096 WGs

#define SLOT4  (S_WG / 4)       // 1152 float4 slots
#define OSLOT4 (OUT / 4)        // 1024
#define WSLOT4 (WU / 4)         // 128

// ws layout (float indices)
#define COEF_OFF 0               // 20
#define POWJ_OFF 64              // j=0..5: A^(18*2^j)      (384)
#define XW1_OFF  448             // A^1152 (wave span)      (64)
#define PLM4_OFF 512             // packed PLM[l]=A^(18l): 10 grp x 64 lane x f4 (2560)
#define WSEQ_OFF 3072            // w_n = C*A^n: 18 x 8     (144)

// LDS: identity float4/float2 slots + wave aggregates
#define WAGG_L (SLOT4 * 4)       // float idx: 4 waves * 8
#define LDS_F  (WAGG_L + 32)     // 4640 floats = 18.6 KB -> 8 WG/CU

// packed block-lower-triangular index maps (rows use cols 0..(r|1))
__device__ __forceinline__ constexpr int prow(int p) {
    return (p < 2) ? 0 : (p < 4) ? 1 : (p < 8) ? 2 : (p < 12) ? 3
         : (p < 18) ? 4 : (p < 24) ? 5 : (p < 32) ? 6 : 7;
}
__device__ __forceinline__ constexpr int pcol(int p) {
    return p - ((p < 2) ? 0 : (p < 4) ? 2 : (p < 8) ? 4 : (p < 12) ? 8
              : (p < 18) ? 12 : (p < 24) ? 18 : (p < 32) ? 24 : 32);
}

// ---------------------------------------------------------------------------
// Precompute (1 block, 64 thr):
//   coefs (f32-rounded);  unit-state sim (double) -> A^18 columns AND the
//   output rows w_n = C*A^n (n=0..17);  squaring chain A^(18*2^j), XW1;
//   PLM[l]=A^(18l) via per-thread binary decomposition (parallel, float).
// ---------------------------------------------------------------------------
__global__ void precompute_k(const float* __restrict__ lr,
                             const float* __restrict__ ra,
                             const float* __restrict__ b0,
                             const float* __restrict__ b1,
                             const float* __restrict__ b2,
                             float* __restrict__ ws) {
    __shared__ double A2d[6][64];
    __shared__ float  A2f[6][64];
    __shared__ double Tw[64];
    const int t = threadIdx.x;  // 64

    if (t < NF) {
        double r   = 0.999 / (1.0 + exp(-(double)lr[t]));
        double ang = 3.14159265358979323846 / (1.0 + exp(-(double)ra[t]));
        ws[COEF_OFF + t * 5 + 0] = b0[t];
        ws[COEF_OFF + t * 5 + 1] = b1[t];
        ws[COEF_OFF + t * 5 + 2] = b2[t];
        ws[COEF_OFF + t * 5 + 3] = (float)(-2.0 * r * cos(ang));
        ws[COEF_OFF + t * 5 + 4] = (float)(r * r);
    }
    __syncthreads();

    if (t < 8) {
        double cb0[NF], cb1[NF], cb2[NF], ca1[NF], ca2[NF];
        for (int f = 0; f < NF; ++f) {
            cb0[f] = (double)ws[COEF_OFF + f * 5 + 0];
            cb1[f] = (double)ws[COEF_OFF + f * 5 + 1];
            cb2[f] = (double)ws[COEF_OFF + f * 5 + 2];
            ca1[f] = (double)ws[COEF_OFF + f * 5 + 3];
            ca2[f] = (double)ws[COEF_OFF + f * 5 + 4];
        }
        double s[8];
        for (int r = 0; r < 8; ++r) s[r] = 0.0;
        s[t] = 1.0;
        for (int n = 0; n < CPT; ++n) {
            double v = 0.0;  // zero input
            for (int f = 0; f < NF; ++f) {
                double y     = cb0[f] * v + s[2 * f];
                s[2 * f]     = cb1[f] * v - ca1[f] * y + s[2 * f + 1];
                s[2 * f + 1] = cb2[f] * v - ca2[f] * y;
                v = y;
            }
            ws[WSEQ_OFF + n * 8 + t] = (float)v;  // w_n[t] = C*A^n*e_t
        }
        for (int r = 0; r < 8; ++r) A2d[0][r * 8 + t] = s[r];  // col t of A^18
    }
    __syncthreads();

    A2f[0][t] = (float)A2d[0][t];
    ws[POWJ_OFF + t] = A2f[0][t];
    const int r8 = t >> 3, c8 = t & 7;
    for (int j = 1; j <= 6; ++j) {
        const double* S = A2d[j - 1];
        double acc = 0.0;
        for (int m = 0; m < 8; ++m) acc += S[r8 * 8 + m] * S[m * 8 + c8];
        Tw[t] = acc;
        __syncthreads();
        if (j <= 5) {
            A2d[j][t] = Tw[t];
            A2f[j][t] = (float)Tw[t];
            ws[POWJ_OFF + j * 64 + t] = (float)Tw[t];
        } else {
            ws[XW1_OFF + t] = (float)Tw[t];  // A^1152
        }
        __syncthreads();
    }

    // PLM[t] = A^(18*t) via binary decomposition (float, per-thread parallel)
    float M[64];
#pragma unroll
    for (int i = 0; i < 64; ++i) M[i] = ((i >> 3) == (i & 7)) ? 1.f : 0.f;
    for (int j = 0; j < 6; ++j) {
        if ((t >> j) & 1) {
            float Tn[64];
            for (int r = 0; r < 8; ++r)
                for (int c = 0; c < 8; ++c) {
                    float acc = 0.f;
                    for (int m = 0; m < 8; ++m)
                        acc = fmaf(M[r * 8 + m], A2f[j][m * 8 + c], acc);
                    Tn[r * 8 + c] = acc;
                }
            for (int i = 0; i < 64; ++i) M[i] = Tn[i];
        }
    }
    for (int p = 0; p < 40; ++p)
        ws[PLM4_OFF + (p >> 2) * 256 + t * 4 + (p & 3)] = M[prow(p) * 8 + pcol(p)];
}

// ---------------------------------------------------------------------------
__device__ __forceinline__ void step1(float& u, float* s,
                                      const float* c0, const float* c1,
                                      const float* c2, const float* A1,
                                      const float* A2) {
#pragma unroll
    for (int f = 0; f < NF; ++f) {
        float yv     = fmaf(c0[f], u, s[2 * f]);
        s[2 * f]     = fmaf(-A1[f], yv, fmaf(c1[f], u, s[2 * f + 1]));
        s[2 * f + 1] = fmaf(-A2[f], yv, c2[f] * u);
        u = yv;
    }
}

// Sparse (block-lower-triangular) matvecs; T wave-uniform (global) -> scalar.
__device__ __forceinline__ void matvec_acc_sp(float* o, const float* __restrict__ T,
                                              const float* p) {
#pragma unroll
    for (int r = 0; r < 8; ++r) {
        const int ncol = (r | 1) + 1;
#pragma unroll
        for (int c = 0; c < 8; ++c)
            if (c < ncol) o[r] = fmaf(T[r * 8 + c], p[c], o[r]);
    }
}
__device__ __forceinline__ void matvec_rep_sp(float* h, const float* __restrict__ T) {
    float tmp[8];
#pragma unroll
    for (int r = 0; r < 8; ++r) {
        const int ncol = (r | 1) + 1;
        float acc = 0.f;
#pragma unroll
        for (int c = 0; c < 8; ++c)
            if (c < ncol) acc = fmaf(T[r * 8 + c], h[c], acc);
        tmp[r] = acc;
    }
#pragma unroll
    for (int r = 0; r < 8; ++r) h[r] = tmp[r];
}

// ---------------------------------------------------------------------------
// One WG = 4096-sample output tile + 512-sample warm-up. No inter-WG comm.
// Single filter pass; exact-state correction via y_n = y0_n + w_n . delta.
// ---------------------------------------------------------------------------
__global__ __launch_bounds__(TPB, 6) void biquad_k(const float* __restrict__ x,
                                                   const float* __restrict__ ws,
                                                   float* __restrict__ y) {
    __shared__ __align__(16) float ldsf[LDS_F];
    float4* lds4 = (float4*)ldsf;
    float2* lds2 = (float2*)ldsf;
    const int t    = threadIdx.x;
    const int lane = t & 63;
    const int w    = t >> 6;

    const int tile = blockIdx.x;
    const int row  = tile / TPR;
    const int tpos = tile % TPR;

    const float* __restrict__ mats = ws + POWJ_OFF;
    const float* __restrict__ xw1  = ws + XW1_OFF;

    // ---- stage x -> LDS (coalesced float4, identity slots) ----
    const long base4 = (long)row * (Ln / 4) + (long)tpos * OSLOT4 - WSLOT4;
    const float4* xg4 = (const float4*)x;
#pragma unroll
    for (int j = 0; j < 4; ++j) {
        const int n4 = j * TPB + t;
        float4 v = make_float4(0.f, 0.f, 0.f, 0.f);
        if (tpos > 0 || n4 >= WSLOT4) v = xg4[base4 + n4];
        lds4[n4] = v;
    }
    if (t < SLOT4 - 4 * TPB) {  // tail slots [1024, 1152)
        const int n4 = 4 * TPB + t;
        lds4[n4] = xg4[base4 + n4];
    }

    float c0[NF], c1[NF], c2[NF], A1[NF], A2[NF];
#pragma unroll
    for (int f = 0; f < NF; ++f) {
        c0[f] = ws[COEF_OFF + f * 5 + 0];
        c1[f] = ws[COEF_OFF + f * 5 + 1];
        c2[f] = ws[COEF_OFF + f * 5 + 2];
        A1[f] = ws[COEF_OFF + f * 5 + 3];
        A2[f] = ws[COEF_OFF + f * 5 + 4];
    }
    __syncthreads();

    // ---- pass 1 (only filter pass): zero-state outputs y0 -> regs, final d ----
    float s[8];
#pragma unroll
    for (int r = 0; r < 8; ++r) s[r] = 0.f;
    float2 xr[CPT / 2];
#pragma unroll
    for (int i = 0; i < CPT / 2; ++i) {
        float2 v = lds2[(CPT / 2) * t + i];
        float u;
        u = v.x; step1(u, s, c0, c1, c2, A1, A2); v.x = u;
        u = v.y; step1(u, s, c0, c1, c2, A1, A2); v.y = u;
        xr[i] = v;  // y0 pair
    }

    // ---- intra-wave affine Kogge-Stone over 64 chunks ----
    float v8[8];
#pragma unroll
    for (int r = 0; r < 8; ++r) v8[r] = s[r];
#pragma unroll
    for (int j = 0; j < 6; ++j) {
        const int st = 1 << j;
        float p[8];
#pragma unroll
        for (int r = 0; r < 8; ++r) p[r] = __shfl_up(v8[r], st, 64);
        if (lane >= st) matvec_acc_sp(v8, mats + j * 64, p);
    }

    if (lane == 63) {
#pragma unroll
        for (int r = 0; r < 8; ++r) ldsf[WAGG_L + w * 8 + r] = v8[r];
    }
    __syncthreads();

    // ---- wave entry H (redundant per-thread Horner, oldest-first) ----
    float H[8];
#pragma unroll
    for (int r = 0; r < 8; ++r) H[r] = 0.f;
#pragma unroll
    for (int m = 0; m < NW - 1; ++m) {
        if (m < w) {
            matvec_rep_sp(H, xw1);
#pragma unroll
            for (int r = 0; r < 8; ++r) H[r] += ldsf[WAGG_L + m * 8 + r];
        }
    }

    // ---- delta = PLM[lane]*H + v8[lane-1] (packed coalesced PLM loads) ----
    float dlt[8];
#pragma unroll
    for (int r = 0; r < 8; ++r) dlt[r] = 0.f;
    {
        const float4* plm4 = (const float4*)(ws + PLM4_OFF);
#pragma unroll
        for (int g = 0; g < 10; ++g) {
            const float4 mv = plm4[g * 64 + lane];
            dlt[prow(4 * g + 0)] = fmaf(mv.x, H[pcol(4 * g + 0)], dlt[prow(4 * g + 0)]);
            dlt[prow(4 * g + 1)] = fmaf(mv.y, H[pcol(4 * g + 1)], dlt[prow(4 * g + 1)]);
            dlt[prow(4 * g + 2)] = fmaf(mv.z, H[pcol(4 * g + 2)], dlt[prow(4 * g + 2)]);
            dlt[prow(4 * g + 3)] = fmaf(mv.w, H[pcol(4 * g + 3)], dlt[prow(4 * g + 3)]);
        }
    }
#pragma unroll
    for (int r = 0; r < 8; ++r) {
        const float pv = __shfl_up(v8[r], 1, 64);
        if (lane > 0) dlt[r] += pv;
    }

    // ---- correction: y_n = y0_n + w_n . delta  (w_n wave-uniform -> scalar) ----
    const float* __restrict__ wsq = ws + WSEQ_OFF;
#pragma unroll
    for (int i = 0; i < CPT / 2; ++i) {
        float a0 = 0.f, a1 = 0.f;
#pragma unroll
        for (int k = 0; k < 8; ++k) {
            a0 = fmaf(wsq[(2 * i) * 8 + k], dlt[k], a0);
            a1 = fmaf(wsq[(2 * i + 1) * 8 + k], dlt[k], a1);
        }
        xr[i].x += a0;
        xr[i].y += a1;
    }

    // ---- y regs -> LDS own slots; coalesced global write ----
#pragma unroll
    for (int i = 0; i < CPT / 2; ++i) lds2[(CPT / 2) * t + i] = xr[i];
    __syncthreads();

    float4* yg4 = (float4*)y;
    const long obase4 = (long)row * (Ln / 4) + (long)tpos * OSLOT4;
#pragma unroll
    for (int j = 0; j < 4; ++j) {
        const int n4 = WSLOT4 + j * TPB + t;  // [128, 1152)
        yg4[obase4 + (n4 - WSLOT4)] = lds4[n4];
    }
}

// ---------------------------------------------------------------------------
extern "C" void kernel_launch(void* const* d_in, const int* in_sizes, int n_in,
                              void* d_out, int out_size, void* d_ws, size_t ws_size,
                              hipStream_t stream) {
    const float* x  = (const float*)d_in[0];
    const float* lr = (const float*)d_in[1];
    const float* ra = (const float*)d_in[2];
    const float* b0 = (const float*)d_in[3];
    const float* b1 = (const float*)d_in[4];
    const float* b2 = (const float*)d_in[5];
    float* y  = (float*)d_out;
    float* ws = (float*)d_ws;

    precompute_k<<<dim3(1), dim3(64), 0, stream>>>(lr, ra, b0, b1, b2, ws);
    biquad_k<<<dim3(NT), dim3(TPB), 0, stream>>>(x, ws, y);
}